// Round 4
// baseline (3859.133 us; speedup 1.0000x reference)
//
#include <hip/hip_runtime.h>
#include <stdint.h>

#define NN 64
#define TT 512
#define DD 512
#define HH 512
#define H3 1536
#define MROWS (NN * TT)   // 32768

#define GRPN 4      // n-groups per dir
#define CBLK 8      // col-blocks per group (rendezvous group size)
#define MN 16       // sequences per n-group

typedef _Float16 f16;
typedef f16 f16x8 __attribute__((ext_vector_type(8)));
typedef float f32x4 __attribute__((ext_vector_type(4)));
typedef unsigned long long ull;

// ws layout (bytes):
//   xm    f16 [2][512][64][1536]                         201,326,592
//   wpack f16 [2][8 cb][8 w][3 t][8 ks][64 lane][8]        3,145,728
//   hbuf  ull slow[2 buf][2 dir][4 g][4096 slots]            524,288
//         + fast (same shape, +65536 slots)                  524,288
//         slot = (u32: 2xf16 h) | (u32 stamp << 32), phys-permuted so a
//         reader thread's 8 slots are one 64B line: phys=(sid&511)*8+(sid>>9)
//   flags u32 [2 dir][4 g][16 (8 used)] = read-done steps         512
#define XM_BYTES    ((size_t)2 * TT * NN * H3 * 2)
#define WPACK_BYTES ((size_t)2 * CBLK * 8 * 3 * 8 * 64 * 8 * 2)
#define FAST_OFF    ((size_t)2 * 2 * GRPN * 4096)        // slots
#define HBUF_BYTES  (FAST_OFF * 8 * 2)                    // slow + fast
#define CNT_BYTES   ((size_t)512)

// ---------------------------------------------------------------------------
// Kernel 1: repack W_h fp32 -> f16 MFMA-B-fragment order.
// Layout: [dir][cb][wave][t(z,r,g)][ks][lane][8j], wave = kh*4 + ug.
//   k = kh*256 + ks*32 + (lane>>4)*8 + j;  col = t*512 + cb*64 + ug*16 + (lane&15)
// grid (8, 2), 256 threads.
// ---------------------------------------------------------------------------
__global__ void repack_wh_frag(const float* __restrict__ whf,
                               const float* __restrict__ whb,
                               f16* __restrict__ wpack) {
    const int cb = blockIdx.x;
    const int dir = blockIdx.y;
    const float* src = dir ? whb : whf;
    f16* dst = wpack + ((size_t)(dir * CBLK + cb)) * 12288 * 8;
    for (int c = threadIdx.x; c < 12288; c += blockDim.x) {
        const int lane = c & 63;
        const int ks = (c >> 6) & 7;
        const int q2 = c >> 9;          // 0..23 = w*3 + t
        const int t = q2 % 3;
        const int w = q2 / 3;
        const int k = (w >> 2) * 256 + ks * 32 + (lane >> 4) * 8;
        const int u = cb * 64 + (w & 3) * 16 + (lane & 15);
        const int gcol = t * 512 + u;
        f16x8 v;
        #pragma unroll
        for (int j = 0; j < 8; ++j)
            v[j] = (f16)src[(size_t)(k + j) * H3 + gcol];
        *(f16x8*)(dst + (size_t)c * 8) = v;
    }
}

// ---------------------------------------------------------------------------
// Kernel 2: xm[dir][t][n][c] = x[n][t][:] @ W_x_dir[:, c]  (fp32 acc, f16 out)
// 128x128 tile, BK=32, 256 threads, 8x8 micro-tile. grid (12, 256, 2).
// ---------------------------------------------------------------------------
__global__ __launch_bounds__(256, 2) void gemm_xw(const float* __restrict__ x,
                                                  const float* __restrict__ wxf,
                                                  const float* __restrict__ wxb,
                                                  f16* __restrict__ xm) {
    const int dir = blockIdx.z;
    const float* w = dir ? wxb : wxf;
    f16* out = xm + (size_t)dir * MROWS * H3;
    const int c0 = blockIdx.x * 128;
    const int r0 = blockIdx.y * 128;
    __shared__ float sA[32][128];
    __shared__ float sB[32][128];
    const int t = threadIdx.x;
    const int tx = t & 15, ty = t >> 4;
    float acc[8][8];
    #pragma unroll
    for (int i = 0; i < 8; ++i)
        #pragma unroll
        for (int j = 0; j < 8; ++j) acc[i][j] = 0.f;

    for (int k0 = 0; k0 < DD; k0 += 32) {
        #pragma unroll
        for (int i = 0; i < 4; ++i) {
            int idx = t * 4 + i;
            int m = idx >> 3;
            int c = idx & 7;
            float4 u = *(const float4*)(x + (size_t)(r0 + m) * DD + k0 + c * 4);
            sA[c * 4 + 0][m] = u.x;
            sA[c * 4 + 1][m] = u.y;
            sA[c * 4 + 2][m] = u.z;
            sA[c * 4 + 3][m] = u.w;
        }
        #pragma unroll
        for (int i = 0; i < 4; ++i) {
            int idx = t * 4 + i;
            int kk = idx >> 5;
            int ch = idx & 31;
            *(float4*)&sB[kk][ch * 4] =
                *(const float4*)(w + (size_t)(k0 + kk) * H3 + c0 + ch * 4);
        }
        __syncthreads();
        for (int k = 0; k < 32; ++k) {
            float4 a0 = *(const float4*)&sA[k][ty * 8];
            float4 a1 = *(const float4*)&sA[k][ty * 8 + 4];
            float4 b0 = *(const float4*)&sB[k][tx * 8];
            float4 b1 = *(const float4*)&sB[k][tx * 8 + 4];
            float a[8] = {a0.x, a0.y, a0.z, a0.w, a1.x, a1.y, a1.z, a1.w};
            float b[8] = {b0.x, b0.y, b0.z, b0.w, b1.x, b1.y, b1.z, b1.w};
            #pragma unroll
            for (int ii = 0; ii < 8; ++ii)
                #pragma unroll
                for (int jj = 0; jj < 8; ++jj)
                    acc[ii][jj] = fmaf(a[ii], b[jj], acc[ii][jj]);
        }
        __syncthreads();
    }
    #pragma unroll
    for (int ii = 0; ii < 8; ++ii) {
        const size_t r = (size_t)(r0 + ty * 8 + ii);
        const size_t tt = r & 511, n = r >> 9;     // row = n*512 + t
        f16x8 v;
        #pragma unroll
        for (int jj = 0; jj < 8; ++jj) v[jj] = (f16)acc[ii][jj];
        *(f16x8*)(out + (tt * 64 + n) * H3 + c0 + tx * 8) = v;
    }
}

// ---------------------------------------------------------------------------
// Batched 8x sc0 (L2-coherent, L1-bypass) 8B loads of one 64B line.
// ---------------------------------------------------------------------------
__device__ __forceinline__ void fast_ld8(const ull* a, ull (&t)[8]) {
    asm volatile(
        "global_load_dwordx2 %0, %8, off sc0\n\t"
        "global_load_dwordx2 %1, %8, off offset:8 sc0\n\t"
        "global_load_dwordx2 %2, %8, off offset:16 sc0\n\t"
        "global_load_dwordx2 %3, %8, off offset:24 sc0\n\t"
        "global_load_dwordx2 %4, %8, off offset:32 sc0\n\t"
        "global_load_dwordx2 %5, %8, off offset:40 sc0\n\t"
        "global_load_dwordx2 %6, %8, off offset:48 sc0\n\t"
        "global_load_dwordx2 %7, %8, off offset:56 sc0\n\t"
        "s_waitcnt vmcnt(0)"
        : "=&v"(t[0]), "=&v"(t[1]), "=&v"(t[2]), "=&v"(t[3]),
          "=&v"(t[4]), "=&v"(t[5]), "=&v"(t[6]), "=&v"(t[7])
        : "v"(a)
        : "memory");
}

// ---------------------------------------------------------------------------
// Kernel 3: 2-D split GRU scan, stamped-slot exchange with XCD-local fast path.
//  - grid is 1-D, remapped so all 8 col-blocks of a group share wgid%8 ->
//    same XCD under round-robin dispatch (performance heuristic only).
//  - publish: plain store (-> home L2) into FAST buffer + agent atomic
//    (-> IC) into SLOW buffer. Readers poll FAST via sc0 loads; every 4th
//    retry round falls back to SLOW agent atomics => progress guaranteed
//    regardless of placement. Stamps self-validate both paths.
//  - anti-clobber RD flags unchanged (IC atomics, 1-step lagged).
// grid (64), 512 threads = 8 waves (kh = k-half, ug = 16-unit group).
// ---------------------------------------------------------------------------
__global__ __launch_bounds__(512, 1) void gru_scan_mfma(
        const f16* __restrict__ xm,
        const f16* __restrict__ wpack,
        const float* __restrict__ b_f, const float* __restrict__ b_b,
        ull* __restrict__ hbuf,
        unsigned int* __restrict__ flags,
        float* __restrict__ out) {
    const int groupid = blockIdx.x & 7;   // -> XCD (heuristic)
    const int cb      = blockIdx.x >> 3;
    const int dir     = groupid & 1;
    const int g       = groupid >> 1;
    const int tid = threadIdx.x;
    const int lane = tid & 63, wave = tid >> 6;
    const int kh = wave >> 2;          // k-half: [kh*256, kh*256+256)
    const int ug = wave & 3;           // unit group: [ug*16, ug*16+16)

    // LDS: h image [16 n][512 u] f16, XOR-swizzled (byte ^= (row&7)<<4), 16 KB
    //      + k-partial exchange part[ug][t][16 n][20 pad] f32, 15 KB
    __shared__ __align__(16) unsigned char himg[16384];
    __shared__ float part[4][3][16][20];

    // B-fragments: resident for all 512 steps (96 VGPR).
    f16x8 bfrag[3][8];
    {
        const f16* wp = wpack +
            ((size_t)(dir * CBLK + cb) * 12288 + (size_t)wave * 1536) * 8;
        #pragma unroll
        for (int t = 0; t < 3; ++t)
            #pragma unroll
            for (int ks = 0; ks < 8; ++ks)
                bfrag[t][ks] = *(const f16x8*)(wp + ((size_t)((t * 8 + ks) * 64 + lane)) * 8);
    }

    const int u_l = cb * 64 + ug * 16 + (lane & 15);  // unit col (kh==0 duty)
    const int nrow0 = (lane >> 4) * 4;                // first of 4 local n-rows
    const float* bias = dir ? b_b : b_f;
    float bz = 0.f, br = 0.f, bg = 0.f;
    if (kh == 0) { bz = bias[u_l]; br = bias[512 + u_l]; bg = bias[1024 + u_l]; }
    const f16* xmd = xm + (size_t)dir * TT * NN * H3;
    unsigned int* rdg = flags + (dir * GRPN + g) * 16;   // 64B line per group

    // A-fragment LDS address: row m = lane&15, k = kh*256 + ks*32 + (lane>>4)*8
    const int fb = (lane & 15) * 1024 + kh * 512 + (lane >> 4) * 16;
    const int fswz = ((lane & 15) & 7) << 4;

    float hprev[4] = {0.f, 0.f, 0.f, 0.f};
    float px[3][4];
    float hnew[4];
    union H16 { f16 h; unsigned short u; };

    // preload xm gate inputs for step 0 (round-0 style: prefetch at loop
    // bottom thereafter so the latency rides the inter-step crossing)
    if (kh == 0) {
        const int tc0 = dir ? (TT - 1) : 0;
        #pragma unroll
        for (int r = 0; r < 4; ++r) {
            const int n = g * 16 + nrow0 + r;
            const size_t ro = ((size_t)tc0 * 64 + n) * H3 + u_l;
            px[0][r] = (float)xmd[ro];
            px[1][r] = (float)xmd[ro + 512];
            px[2][r] = (float)xmd[ro + 1024];
        }
    }

    for (int s = 0; s < TT; ++s) {
        const int tc = dir ? (TT - 1 - s) : s;

        // ---- stage h(s): fast (L2/sc0) poll, slow (IC/atomic) fallback ----
        ull tmp[8];
        {
            const ull* sb8 = hbuf +
                (((size_t)(s & 1) * 2 + dir) * GRPN + g) * 4096 + tid * 8;
            const ull* fb8 = sb8 + FAST_OFF;
            fast_ld8(fb8, tmp);
            const unsigned int want = (unsigned int)s;
            int rounds = 0;
            for (;;) {
                bool bad = false;
                #pragma unroll
                for (int i = 0; i < 8; ++i)
                    bad |= ((unsigned int)(tmp[i] >> 32) < want);
                if (!__any(bad)) break;
                ++rounds;
                if ((rounds & 3) == 0) {
                    // guaranteed-progress IC round
                    #pragma unroll
                    for (int i = 0; i < 8; ++i)
                        if ((unsigned int)(tmp[i] >> 32) < want)
                            tmp[i] = __hip_atomic_load(sb8 + i,
                                        __ATOMIC_RELAXED, __HIP_MEMORY_SCOPE_AGENT);
                    __builtin_amdgcn_s_sleep(1);
                } else {
                    ull t2[8];
                    fast_ld8(fb8, t2);
                    #pragma unroll
                    for (int i = 0; i < 8; ++i)
                        if ((unsigned int)(tmp[i] >> 32) < want) tmp[i] = t2[i];
                }
            }
            // tmp[i] == slot sid = i*512 + tid (phys permutation inverse)
            #pragma unroll
            for (int i = 0; i < 8; ++i) {
                const int off = (i * 512 + tid) * 4;   // 4B of h per slot
                const int row = off >> 10;
                *(unsigned int*)(himg + (off ^ ((row & 7) << 4))) =
                    (unsigned int)tmp[i];
            }
        }
        __syncthreads();   // (D) h image complete; all staging loads done

        // read-done: causally sound (loads completed before this store issues)
        if (tid == 0)
            __hip_atomic_store(&rdg[cb], (unsigned int)(s + 1),
                               __ATOMIC_RELAXED, __HIP_MEMORY_SCOPE_AGENT);

        // ---- recurrent matmul: 3 N-tiles (z,r,g) x 8 ks over this k-half ----
        f32x4 a0 = {0.f, 0.f, 0.f, 0.f};
        f32x4 a1 = {0.f, 0.f, 0.f, 0.f};
        f32x4 a2 = {0.f, 0.f, 0.f, 0.f};
        #pragma unroll
        for (int ks = 0; ks < 8; ++ks) {
            f16x8 av = *(const f16x8*)(himg + ((fb + ks * 64) ^ fswz));
            a0 = __builtin_amdgcn_mfma_f32_16x16x32_f16(av, bfrag[0][ks], a0, 0, 0, 0);
            a1 = __builtin_amdgcn_mfma_f32_16x16x32_f16(av, bfrag[1][ks], a1, 0, 0, 0);
            a2 = __builtin_amdgcn_mfma_f32_16x16x32_f16(av, bfrag[2][ks], a2, 0, 0, 0);
        }
        if (kh == 1) {
            #pragma unroll
            for (int r = 0; r < 4; ++r) {
                part[ug][0][nrow0 + r][lane & 15] = a0[r];
                part[ug][1][nrow0 + r][lane & 15] = a1[r];
                part[ug][2][nrow0 + r][lane & 15] = a2[r];
            }
        }
        __syncthreads();   // (E) partials visible

        if (kh == 0) {
            // ---- k-reduce + gate math: z,r,g all local to this lane ----
            #pragma unroll
            for (int r = 0; r < 4; ++r) {
                const float sz = px[0][r] + a0[r] + part[ug][0][nrow0 + r][lane & 15] + bz;
                const float sr = px[1][r] + a1[r] + part[ug][1][nrow0 + r][lane & 15] + br;
                const float hg = a2[r] + part[ug][2][nrow0 + r][lane & 15];
                const float z  = 1.f / (1.f + __expf(-sz));
                const float rr = 1.f / (1.f + __expf(-sr));
                const float gg = 1.f - 2.f / (1.f + __expf(2.f * (px[2][r] + rr * hg + bg)));
                hnew[r] = (1.f - z) * gg + z * hprev[r];
                hprev[r] = hnew[r];
            }
        } else if (wave == 4 && s > 0) {
            // anti-clobber gate (1-step lagged, normally already satisfied):
            // publish of h(s+1) overwrites h(s-1); need all RD >= s.
            const unsigned int tgt = (unsigned int)s;
            while (true) {
                unsigned int v = __hip_atomic_load(&rdg[lane & 7],
                            __ATOMIC_RELAXED, __HIP_MEMORY_SCOPE_AGENT);
                if (__all(v >= tgt)) break;
                __builtin_amdgcn_s_sleep(1);
            }
        }
        __syncthreads();   // (F) himg reads done + clobber gate passed

        if (kh == 0) {
            if (s < TT - 1) {
                // ---- publish h(s+1) FIRST (critical path), dual path ----
                ull* nslab = hbuf +
                    (((size_t)((s + 1) & 1) * 2 + dir) * GRPN + g) * 4096;
                #pragma unroll
                for (int r = 0; r < 4; ++r) {
                    H16 hx; hx.h = (f16)hnew[r];
                    const unsigned int ob = (unsigned int)__shfl_xor((int)hx.u, 1, 64);
                    if (!(lane & 1)) {
                        const ull pk = (ull)((unsigned int)hx.u | (ob << 16))
                                     | ((ull)(s + 1) << 32);
                        const int sid = (nrow0 + r) * 256 + (u_l >> 1);
                        ull* sa = nslab + (((sid & 511) << 3) + (sid >> 9));
                        ull* fa = sa + FAST_OFF;
                        asm volatile("global_store_dwordx2 %0, %1, off"
                                     :: "v"(fa), "v"(pk) : "memory");
                        __hip_atomic_store(sa, pk,
                                __ATOMIC_RELAXED, __HIP_MEMORY_SCOPE_AGENT);
                    }
                }
            }
            #pragma unroll
            for (int r = 0; r < 4; ++r) {
                const int n = g * 16 + nrow0 + r;
                out[((size_t)n * TT + tc) * 1024 + dir * 512 + u_l] = hnew[r];
            }
            if (s < TT - 1) {
                // prefetch next-step xm gate inputs (latency rides the crossing)
                const int tcn = dir ? (TT - 2 - s) : (s + 1);
                #pragma unroll
                for (int r = 0; r < 4; ++r) {
                    const int n = g * 16 + nrow0 + r;
                    const size_t ro = ((size_t)tcn * 64 + n) * H3 + u_l;
                    px[0][r] = (float)xmd[ro];
                    px[1][r] = (float)xmd[ro + 512];
                    px[2][r] = (float)xmd[ro + 1024];
                }
            }
        }
        // no end-of-step barrier: stamps handle data-ready, RD handles clobber
    }
}

// ---------------------------------------------------------------------------
// Zero-workspace fallback (correct but slow).
// ---------------------------------------------------------------------------
__global__ __launch_bounds__(512) void gru_scan_fused(const float* __restrict__ x,
                                                      const float* __restrict__ wxf,
                                                      const float* __restrict__ whf,
                                                      const float* __restrict__ b_f,
                                                      const float* __restrict__ wxb,
                                                      const float* __restrict__ whb,
                                                      const float* __restrict__ b_b,
                                                      float* __restrict__ out) {
    const int n = blockIdx.x;
    const int dir = blockIdx.y;
    const int tid = threadIdx.x;
    const float* wx = dir ? wxb : wxf;
    const float* wh = dir ? whb : whf;
    const float* bias = dir ? b_b : b_f;
    const float bz = bias[tid];
    const float br = bias[512 + tid];
    const float bg = bias[1024 + tid];

    __shared__ float sh[512];
    __shared__ float shx[512];
    sh[tid] = 0.f;
    float hprev = 0.f;
    __syncthreads();

    for (int s = 0; s < TT; ++s) {
        const int tc = dir ? (TT - 1 - s) : s;
        shx[tid] = x[((size_t)n * TT + tc) * DD + tid];
        __syncthreads();
        float az = 0.f, ar = 0.f, ag = 0.f;
        float xz = 0.f, xr = 0.f, xg = 0.f;
        #pragma unroll 2
        for (int k = 0; k < DD; ++k) {
            const float hk = sh[k];
            const float xk = shx[k];
            const size_t rowb = (size_t)k * H3 + tid;
            az = fmaf(wh[rowb], hk, az);
            ar = fmaf(wh[rowb + 512], hk, ar);
            ag = fmaf(wh[rowb + 1024], hk, ag);
            xz = fmaf(wx[rowb], xk, xz);
            xr = fmaf(wx[rowb + 512], xk, xr);
            xg = fmaf(wx[rowb + 1024], xk, xg);
        }
        const float z = 1.f / (1.f + __expf(-(xz + az + bz)));
        const float r = 1.f / (1.f + __expf(-(xr + ar + br)));
        const float g = 1.f - 2.f / (1.f + __expf(2.f * (xg + r * ag + bg)));
        const float hnew = (1.f - z) * g + z * hprev;
        __syncthreads();
        sh[tid] = hnew;
        hprev = hnew;
        out[((size_t)n * TT + tc) * 1024 + (size_t)dir * 512 + tid] = hnew;
        __syncthreads();
    }
}

// ---------------------------------------------------------------------------
extern "C" void kernel_launch(void* const* d_in, const int* in_sizes, int n_in,
                              void* d_out, int out_size, void* d_ws, size_t ws_size,
                              hipStream_t stream) {
    const float* x   = (const float*)d_in[0];
    const float* wxf = (const float*)d_in[1];
    const float* whf = (const float*)d_in[2];
    const float* bf_ = (const float*)d_in[3];
    const float* wxb = (const float*)d_in[4];
    const float* whb = (const float*)d_in[5];
    const float* bb_ = (const float*)d_in[6];
    float* out = (float*)d_out;

    const size_t need = XM_BYTES + WPACK_BYTES + HBUF_BYTES + CNT_BYTES; // ~205.5 MB

    if (ws_size >= need) {
        f16* xm = (f16*)d_ws;
        f16* wpack = (f16*)((char*)d_ws + XM_BYTES);
        ull* hbuf = (ull*)((char*)d_ws + XM_BYTES + WPACK_BYTES);
        unsigned int* flags = (unsigned int*)((char*)d_ws + XM_BYTES + WPACK_BYTES + HBUF_BYTES);
        // zero h slabs (h0 = 0, stamp 0 == valid for step 0) and RD flags
        hipMemsetAsync(hbuf, 0, HBUF_BYTES + CNT_BYTES, stream);
        repack_wh_frag<<<dim3(CBLK, 2), 256, 0, stream>>>(whf, whb, wpack);
        gemm_xw<<<dim3(12, 256, 2), 256, 0, stream>>>(x, wxf, wxb, xm);
        gru_scan_mfma<<<dim3(64), 512, 0, stream>>>(xm, wpack, bf_, bb_,
                                                    hbuf, flags, out);
    } else {
        gru_scan_fused<<<dim3(64, 2), 512, 0, stream>>>(x, wxf, whf, bf_,
                                                        wxb, whb, bb_, out);
    }
}